// Round 5
// baseline (218.828 us; speedup 1.0000x reference)
//
#include <hip/hip_runtime.h>
#include <hip/hip_bf16.h>

typedef __bf16 bf16x8 __attribute__((ext_vector_type(8)));
typedef __bf16 bf16x4 __attribute__((ext_vector_type(4)));
typedef __bf16 bf16x2 __attribute__((ext_vector_type(2)));
typedef float  f32x4  __attribute__((ext_vector_type(4)));

#define NB   4
#define C_   256
#define CI_  128
#define NSP  8192   // 8*32*32
#define NKV  2048   // 8*16*16
#define KVT  32     // kv rows per tile
#define NT   (NKV/KVT)

// direct global->LDS DMA, 16B per lane. g: per-lane source; l: wave-uniform dest.
__device__ __forceinline__ void gload_lds16(const void* g, void* l) {
    __builtin_amdgcn_global_load_lds(
        (const __attribute__((address_space(1))) void*)(unsigned long long)(uintptr_t)g,
        (__attribute__((address_space(3))) void*)(unsigned)(uintptr_t)l,
        16, 0, 0);
}

// ---------------- kernel 0: weight prep (bf16 cast, BN fold) ----------------
__global__ __launch_bounds__(256) void prep_kernel(
    const float* __restrict__ g_w,  const float* __restrict__ g_b,
    const float* __restrict__ th_w, const float* __restrict__ th_b,
    const float* __restrict__ ph_w, const float* __restrict__ ph_b,
    const float* __restrict__ w_w,  const float* __restrict__ w_b,
    const float* __restrict__ bn_g, const float* __restrict__ bn_be,
    const float* __restrict__ bn_m, const float* __restrict__ bn_v,
    __bf16* __restrict__ w_all, __bf16* __restrict__ w2,
    float* __restrict__ b_all, float* __restrict__ bnA, float* __restrict__ bnB)
{
    int idx = blockIdx.x * 256 + threadIdx.x;
    if (idx < 98304) {                       // w_all: [theta;phi;g] 384x256
        int o = idx >> 8, c = idx & 255;
        float v;
        if (o < 128)      v = th_w[o*256 + c];
        else if (o < 256) v = ph_w[(o-128)*256 + c];
        else              v = g_w[(o-256)*256 + c];
        w_all[idx] = (__bf16)v;
    } else if (idx < 131072) {               // w2: 256x128
        int j = idx - 98304;
        w2[j] = (__bf16)w_w[j];
    } else if (idx < 131456) {               // b_all: 384
        int k = idx - 131072;
        float v;
        if (k < 128) v = th_b[k]; else if (k < 256) v = ph_b[k-128]; else v = g_b[k-256];
        b_all[k] = v;
    } else if (idx < 131712) {               // BN fold (+w_b): 256
        int m = idx - 131456;
        float sc = bn_g[m] * rsqrtf(bn_v[m] + 1e-5f);
        bnA[m] = sc;
        bnB[m] = w_b[m]*sc + bn_be[m] - bn_m[m]*sc;
    }
}

// ---------------- kernel 1: fused 3-way projection + (1,2,2) maxpool ----------------
__global__ __launch_bounds__(256, 2) void proj_kernel(
    const float* __restrict__ x, const __bf16* __restrict__ w_all,
    const float* __restrict__ b_all,
    __bf16* __restrict__ Q, __bf16* __restrict__ K, __bf16* __restrict__ VT)
{
    const int b    = blockIdx.x >> 7;
    const int tile = blockIdx.x & 127;
    const int n0   = tile * 64;
    const int w    = threadIdx.x >> 6;
    const int lane = threadIdx.x & 63;
    const int lq   = lane & 15;
    const int g    = lane >> 4;

    const float* xb = x + b * (C_ * NSP);

    f32x4 acc[4][6];
    #pragma unroll
    for (int a = 0; a < 4; ++a)
        #pragma unroll
        for (int o = 0; o < 6; ++o) acc[a][o] = (f32x4){0.f,0.f,0.f,0.f};

    #pragma unroll 1
    for (int ck = 0; ck < 8; ++ck) {
        const int cbase = ck*32 + g*8;
        bf16x8 afr[4];
        #pragma unroll
        for (int nf = 0; nf < 4; ++nf) {
            const int n = n0 + nf*16 + lq;
            const float* xp = xb + cbase*NSP + n;
            bf16x8 v;
            #pragma unroll
            for (int e = 0; e < 8; ++e) v[e] = (__bf16)xp[e*NSP];
            afr[nf] = v;
        }
        #pragma unroll
        for (int oi = 0; oi < 6; ++oi) {
            const int orow = (w*6 + oi)*16 + lq;
            bf16x8 bfr = *(const bf16x8*)(w_all + orow*256 + cbase);
            #pragma unroll
            for (int nf = 0; nf < 4; ++nf)
                acc[nf][oi] = __builtin_amdgcn_mfma_f32_16x16x32_bf16(afr[nf], bfr, acc[nf][oi], 0,0,0);
        }
    }

    const int t  = n0 >> 10;
    const int h0 = (n0 & 1023) >> 5;             // even
    const int kvrow0 = t*256 + (h0 >> 1)*16;

    #pragma unroll
    for (int oi = 0; oi < 6; ++oi) {
        const int ocol = (w*6 + oi)*16 + lq;
        const float bias = b_all[ocol];
        float v[4][4];
        #pragma unroll
        for (int nf = 0; nf < 4; ++nf)
            #pragma unroll
            for (int i = 0; i < 4; ++i) v[nf][i] = acc[nf][oi][i] + bias;

        const int seg = ocol >> 7;
        const int ol  = ocol & 127;
        if (seg == 0) {                      // theta -> Q[b][n][ol]
            #pragma unroll
            for (int nf = 0; nf < 4; ++nf)
                #pragma unroll
                for (int i = 0; i < 4; ++i) {
                    int n = n0 + nf*16 + g*4 + i;
                    Q[(b*NSP + n)*CI_ + ol] = (__bf16)v[nf][i];
                }
        } else if (seg == 1) {               // phi -> pool -> K[b][nkv][ol]
            #pragma unroll
            for (int nfp = 0; nfp < 2; ++nfp)
                #pragma unroll
                for (int j = 0; j < 2; ++j) {
                    float pv = fmaxf(fmaxf(v[nfp][2*j], v[nfp][2*j+1]),
                                     fmaxf(v[nfp+2][2*j], v[nfp+2][2*j+1]));
                    int wp = nfp*8 + g*2 + j;
                    K[(b*NKV + kvrow0 + wp)*CI_ + ol] = (__bf16)pv;
                }
        } else {                             // g -> pool -> VT[b][ol][nkv]
            #pragma unroll
            for (int nfp = 0; nfp < 2; ++nfp) {
                bf16x2 pk;
                #pragma unroll
                for (int j = 0; j < 2; ++j) {
                    float pv = fmaxf(fmaxf(v[nfp][2*j], v[nfp][2*j+1]),
                                     fmaxf(v[nfp+2][2*j], v[nfp+2][2*j+1]));
                    pk[j] = (__bf16)pv;
                }
                int wp = nfp*8 + g*2;
                *(bf16x2*)(VT + (b*CI_ + ol)*NKV + kvrow0 + wp) = pk;
            }
        }
    }
}

// ---------------- kernel 2: flash attention, LDS-staged K/V, 32 q per wave ----------------
// Each K/V fragment read from LDS now feeds TWO MFMAs (two q-subtiles per wave),
// halving LDS-read bytes per q. Block = 4 waves x 32 q = 128 q; grid = 256 (1/CU).
__global__ __launch_bounds__(256, 1) void attn_kernel(
    const __bf16* __restrict__ Q, const __bf16* __restrict__ K,
    const __bf16* __restrict__ VT, __bf16* __restrict__ yy)
{
    __shared__ __bf16 kbuf[3][32*128];
    __shared__ __bf16 vbuf[3][128*32];
    __shared__ __bf16 plds[4][32][40];       // per-wave P buffer, rows s*16+lq, 80B stride

    const int b    = blockIdx.x >> 6;
    const int qt   = blockIdx.x & 63;
    const int w    = threadIdx.x >> 6;
    const int lane = threadIdx.x & 63;
    const int lq   = lane & 15;
    const int g    = lane >> 4;
    const int q0   = qt*128 + w*32;
    const float LOG2E = 1.4426950408889634f;

    // Q fragments (B-operand: col q = lane&15, k = d), two q-subtiles
    bf16x8 qf[2][4];
    #pragma unroll
    for (int s = 0; s < 2; ++s) {
        const __bf16* qrow = Q + (size_t)(b*NSP + q0 + s*16 + lq)*CI_;
        #pragma unroll
        for (int kk = 0; kk < 4; ++kk) qf[s][kk] = *(const bf16x8*)(qrow + kk*32 + g*8);
    }

    float m_run[2] = {-1e30f, -1e30f}, l_run[2] = {0.f, 0.f};
    f32x4 oacc[2][8];
    #pragma unroll
    for (int s = 0; s < 2; ++s)
        #pragma unroll
        for (int d = 0; d < 8; ++d) oacc[s][d] = (f32x4){0.f,0.f,0.f,0.f};

    const __bf16* Kb0 = K  + (size_t)b*NKV*CI_;
    const __bf16* Vb0 = VT + (size_t)b*CI_*NKV;
    __bf16* pw = &plds[w][0][0];

    // stage one kv-tile into buffer bi: 4 global_load_lds per wave (2 K + 2 V)
    auto stage = [&](int bi, int kv0) {
        #pragma unroll
        for (int j = 0; j < 2; ++j) {
            int o   = w*2048 + j*1024 + lane*16;       // byte offset in 8KB tile
            int row = o >> 8;                          // K row (0..31)
            int c   = (o & 255) ^ ((row & 7) << 4);    // inverse swizzle on source
            const __bf16* src = Kb0 + (size_t)(kv0 + row)*CI_ + (c >> 1);
            gload_lds16(src, (char*)&kbuf[bi][0] + w*2048 + j*1024);
        }
        #pragma unroll
        for (int j = 0; j < 2; ++j) {
            int o    = w*2048 + j*1024 + lane*16;
            int row  = o >> 6;                         // V row (d, 0..127)
            int slot = (o >> 4) & 3;
            int kc   = slot ^ ((row >> 1) & 3);        // inverse swizzle on source
            const __bf16* src = Vb0 + (size_t)row*NKV + kv0 + kc*8;
            gload_lds16(src, (char*)&vbuf[bi][0] + w*2048 + j*1024);
        }
    };

    // prologue: tiles 0 and 1 in flight
    stage(0, 0);
    stage(1, KVT);

    for (int t = 0; t < NT; ++t) {
        // wait for tile t's 4 DMAs (tile t+1's stay in flight), then block sync
        asm volatile("s_waitcnt vmcnt(4)" ::: "memory");
        __builtin_amdgcn_s_barrier();
        __builtin_amdgcn_sched_barrier(0);

        // prefetch tile t+2 (clamped re-stage near the end keeps vmcnt math valid)
        {
            int tn = t + 2;
            int kvn = (tn < NT ? tn : NT-1) * KVT;
            stage(tn % 3, kvn);
        }

        const int bi = t % 3;
        const char* kb = (const char*)&kbuf[bi][0];
        const char* vb = (const char*)&vbuf[bi][0];

        // QK^T: f^T[n][q] = sum_d K[n][d] Q[q][d]; each kf feeds both q-subtiles
        f32x4 facc[2][2];
        #pragma unroll
        for (int s = 0; s < 2; ++s)
            #pragma unroll
            for (int nf = 0; nf < 2; ++nf) facc[s][nf] = (f32x4){0.f,0.f,0.f,0.f};
        __builtin_amdgcn_s_setprio(1);
        #pragma unroll
        for (int kk = 0; kk < 4; ++kk) {
            #pragma unroll
            for (int nf = 0; nf < 2; ++nf) {
                int row = nf*16 + lq;
                int c   = (kk*64 + g*16) ^ ((row & 7) << 4);
                bf16x8 kf = *(const bf16x8*)(kb + row*256 + c);
                facc[0][nf] = __builtin_amdgcn_mfma_f32_16x16x32_bf16(kf, qf[0][kk], facc[0][nf], 0,0,0);
                facc[1][nf] = __builtin_amdgcn_mfma_f32_16x16x32_bf16(kf, qf[1][kk], facc[1][nf], 0,0,0);
            }
        }
        __builtin_amdgcn_s_setprio(0);

        // online softmax per q-subtile (tree reduce, defer-max)
        #pragma unroll
        for (int s = 0; s < 2; ++s) {
            float m0 = fmaxf(fmaxf(facc[s][0][0], facc[s][0][1]), fmaxf(facc[s][0][2], facc[s][0][3]));
            float m1 = fmaxf(fmaxf(facc[s][1][0], facc[s][1][1]), fmaxf(facc[s][1][2], facc[s][1][3]));
            float pmax = fmaxf(m0, m1);
            pmax = fmaxf(pmax, __shfl_xor(pmax, 16, 64));
            pmax = fmaxf(pmax, __shfl_xor(pmax, 32, 64));
            if (!__all(pmax - m_run[s] <= 8.f)) {
                float mnew = fmaxf(m_run[s], pmax);
                float corr = __builtin_amdgcn_exp2f((m_run[s] - mnew) * LOG2E);
                l_run[s] *= corr;
                #pragma unroll
                for (int d = 0; d < 8; ++d) {
                    oacc[s][d][0] *= corr; oacc[s][d][1] *= corr;
                    oacc[s][d][2] *= corr; oacc[s][d][3] *= corr;
                }
                m_run[s] = mnew;
            }
            float p[8];
            #pragma unroll
            for (int nf = 0; nf < 2; ++nf)
                #pragma unroll
                for (int i = 0; i < 4; ++i)
                    p[nf*4+i] = __builtin_amdgcn_exp2f((facc[s][nf][i] - m_run[s]) * LOG2E);
            float ps = ((p[0]+p[1]) + (p[2]+p[3])) + ((p[4]+p[5]) + (p[6]+p[7]));
            ps += __shfl_xor(ps, 16, 64);
            ps += __shfl_xor(ps, 32, 64);
            l_run[s] += ps;
            #pragma unroll
            for (int nf = 0; nf < 2; ++nf) {
                bf16x4 pk;
                #pragma unroll
                for (int i = 0; i < 4; ++i) pk[i] = (__bf16)p[nf*4+i];
                *(bf16x4*)(pw + (s*16 + lq)*40 + nf*16 + g*4) = pk;
            }
        }
        bf16x8 pb[2];
        #pragma unroll
        for (int s = 0; s < 2; ++s)
            pb[s] = *(const bf16x8*)(pw + (s*16 + lq)*40 + g*8);

        // yy^T[d][q] += VT[d][n] * P^T[n][q]; each vf feeds both q-subtiles
        __builtin_amdgcn_s_setprio(1);
        #pragma unroll
        for (int df = 0; df < 8; ++df) {
            int row = df*16 + lq;
            int cb  = (g*16) ^ (((row >> 1) & 3) << 4);
            bf16x8 vf = *(const bf16x8*)(vb + row*64 + cb);
            oacc[0][df] = __builtin_amdgcn_mfma_f32_16x16x32_bf16(vf, pb[0], oacc[0][df], 0,0,0);
            oacc[1][df] = __builtin_amdgcn_mfma_f32_16x16x32_bf16(vf, pb[1], oacc[1][df], 0,0,0);
        }
        __builtin_amdgcn_s_setprio(0);
    }

    #pragma unroll
    for (int s = 0; s < 2; ++s) {
        float inv = 1.f / l_run[s];
        __bf16* yrow = yy + (size_t)(b*NSP + q0 + s*16 + lq)*CI_;
        #pragma unroll
        for (int df = 0; df < 8; ++df) {
            bf16x4 ov;
            #pragma unroll
            for (int i = 0; i < 4; ++i) ov[i] = (__bf16)(oacc[s][df][i] * inv);
            *(bf16x4*)(yrow + df*16 + g*4) = ov;
        }
    }
}

// ---------------- kernel 3: out-proj + BN + residual (vectorized I/O) ----------------
// mfma(A=yy rows n, B=w2 cols co) -> C[n][co]: each lane holds 4 CONSECUTIVE n
// for fixed co -> f32x4 x-read / out-write.
__global__ __launch_bounds__(256, 2) void out_kernel(
    const __bf16* __restrict__ yy, const __bf16* __restrict__ w2,
    const float* __restrict__ bnA, const float* __restrict__ bnB,
    const float* __restrict__ x, float* __restrict__ out)
{
    const int b    = blockIdx.x >> 7;
    const int tile = blockIdx.x & 127;
    const int n0   = tile * 64;
    const int w    = threadIdx.x >> 6;
    const int lane = threadIdx.x & 63;
    const int lq   = lane & 15;
    const int g    = lane >> 4;

    f32x4 acc[4][4];   // [cf][nf], C[n][co]
    #pragma unroll
    for (int a = 0; a < 4; ++a)
        #pragma unroll
        for (int o = 0; o < 4; ++o) acc[a][o] = (f32x4){0.f,0.f,0.f,0.f};

    #pragma unroll
    for (int kk = 0; kk < 4; ++kk) {
        bf16x8 afr[4];   // yy n-row fragments (A-operand)
        #pragma unroll
        for (int nf = 0; nf < 4; ++nf)
            afr[nf] = *(const bf16x8*)(yy + (size_t)(b*NSP + n0 + nf*16 + lq)*CI_ + kk*32 + g*8);
        #pragma unroll
        for (int cf = 0; cf < 4; ++cf) {
            const int corow = (w*4 + cf)*16 + lq;
            bf16x8 bfr = *(const bf16x8*)(w2 + corow*CI_ + kk*32 + g*8);  // B-operand (cols co)
            #pragma unroll
            for (int nf = 0; nf < 4; ++nf)
                acc[cf][nf] = __builtin_amdgcn_mfma_f32_16x16x32_bf16(afr[nf], bfr, acc[cf][nf], 0,0,0);
        }
    }

    #pragma unroll
    for (int cf = 0; cf < 4; ++cf) {
        const int co = (w*4 + cf)*16 + lq;
        const float A = bnA[co], Bv = bnB[co];
        #pragma unroll
        for (int nf = 0; nf < 4; ++nf) {
            const int n = n0 + nf*16 + g*4;
            size_t idx = (size_t)(b*C_ + co)*NSP + n;
            f32x4 xv = *(const f32x4*)(x + idx);
            f32x4 ov;
            #pragma unroll
            for (int i = 0; i < 4; ++i) ov[i] = acc[cf][nf][i]*A + Bv + xv[i];
            *(f32x4*)(out + idx) = ov;
        }
    }
}

// ---------------- launcher ----------------
extern "C" void kernel_launch(void* const* d_in, const int* in_sizes, int n_in,
                              void* d_out, int out_size, void* d_ws, size_t ws_size,
                              hipStream_t stream)
{
    const float* x    = (const float*)d_in[0];
    const float* g_w  = (const float*)d_in[1];
    const float* g_b  = (const float*)d_in[2];
    const float* th_w = (const float*)d_in[3];
    const float* th_b = (const float*)d_in[4];
    const float* ph_w = (const float*)d_in[5];
    const float* ph_b = (const float*)d_in[6];
    const float* w_w  = (const float*)d_in[7];
    const float* w_b  = (const float*)d_in[8];
    const float* bn_g = (const float*)d_in[9];
    const float* bn_be= (const float*)d_in[10];
    const float* bn_m = (const float*)d_in[11];
    const float* bn_v = (const float*)d_in[12];

    char* ws = (char*)d_ws;
    size_t off = 0;
    auto alloc = [&](size_t bytes) -> void* {
        void* p = ws + off;
        off += (bytes + 255) & ~(size_t)255;
        return p;
    };
    __bf16* w_all = (__bf16*)alloc(384*256*2);
    __bf16* w2    = (__bf16*)alloc(256*128*2);
    float*  b_all = (float*) alloc(384*4);
    float*  bnA   = (float*) alloc(256*4);
    float*  bnB   = (float*) alloc(256*4);
    __bf16* Qb    = (__bf16*)alloc((size_t)NB*NSP*CI_*2);
    __bf16* Kb    = (__bf16*)alloc((size_t)NB*NKV*CI_*2);
    __bf16* Vt    = (__bf16*)alloc((size_t)NB*CI_*NKV*2);
    __bf16* yyb   = (__bf16*)alloc((size_t)NB*NSP*CI_*2);

    prep_kernel<<<515, 256, 0, stream>>>(g_w, g_b, th_w, th_b, ph_w, ph_b, w_w, w_b,
                                         bn_g, bn_be, bn_m, bn_v,
                                         w_all, w2, b_all, bnA, bnB);
    proj_kernel<<<512, 256, 0, stream>>>(x, w_all, b_all, Qb, Kb, Vt);
    attn_kernel<<<256, 256, 0, stream>>>(Qb, Kb, Vt, yyb);
    out_kernel <<<512, 256, 0, stream>>>(yyb, w2, bnA, bnB, x, (float*)d_out);
}

// Round 6
// 195.966 us; speedup vs baseline: 1.1167x; 1.1167x over previous
//
#include <hip/hip_runtime.h>
#include <hip/hip_bf16.h>

typedef __bf16 bf16x8 __attribute__((ext_vector_type(8)));
typedef __bf16 bf16x4 __attribute__((ext_vector_type(4)));
typedef __bf16 bf16x2 __attribute__((ext_vector_type(2)));
typedef float  f32x4  __attribute__((ext_vector_type(4)));
typedef float  f32x2  __attribute__((ext_vector_type(2)));

#define NB   4
#define C_   256
#define CI_  128
#define NSP  8192   // 8*32*32
#define NKV  2048   // 8*16*16
#define KVT  32     // kv rows per tile
#define NTH  ((NKV/2)/KVT)   // tiles per kv-half = 32
#define NROW (NB*NSP)        // total q rows

// direct global->LDS DMA, 16B per lane. g: per-lane source; l: wave-uniform dest.
__device__ __forceinline__ void gload_lds16(const void* g, void* l) {
    __builtin_amdgcn_global_load_lds(
        (const __attribute__((address_space(1))) void*)(unsigned long long)(uintptr_t)g,
        (__attribute__((address_space(3))) void*)(unsigned)(uintptr_t)l,
        16, 0, 0);
}

// ---------------- kernel 0: weight prep (bf16 cast, BN fold) ----------------
__global__ __launch_bounds__(256) void prep_kernel(
    const float* __restrict__ g_w,  const float* __restrict__ g_b,
    const float* __restrict__ th_w, const float* __restrict__ th_b,
    const float* __restrict__ ph_w, const float* __restrict__ ph_b,
    const float* __restrict__ w_w,  const float* __restrict__ w_b,
    const float* __restrict__ bn_g, const float* __restrict__ bn_be,
    const float* __restrict__ bn_m, const float* __restrict__ bn_v,
    __bf16* __restrict__ w_all, __bf16* __restrict__ w2,
    float* __restrict__ b_all, float* __restrict__ bnA, float* __restrict__ bnB)
{
    int idx = blockIdx.x * 256 + threadIdx.x;
    if (idx < 98304) {                       // w_all: [theta;phi;g] 384x256
        int o = idx >> 8, c = idx & 255;
        float v;
        if (o < 128)      v = th_w[o*256 + c];
        else if (o < 256) v = ph_w[(o-128)*256 + c];
        else              v = g_w[(o-256)*256 + c];
        w_all[idx] = (__bf16)v;
    } else if (idx < 131072) {               // w2: 256x128
        int j = idx - 98304;
        w2[j] = (__bf16)w_w[j];
    } else if (idx < 131456) {               // b_all: 384
        int k = idx - 131072;
        float v;
        if (k < 128) v = th_b[k]; else if (k < 256) v = ph_b[k-128]; else v = g_b[k-256];
        b_all[k] = v;
    } else if (idx < 131712) {               // BN fold (+w_b): 256
        int m = idx - 131456;
        float sc = bn_g[m] * rsqrtf(bn_v[m] + 1e-5f);
        bnA[m] = sc;
        bnB[m] = w_b[m]*sc + bn_be[m] - bn_m[m]*sc;
    }
}

// ---------------- kernel 1: fused 3-way projection + (1,2,2) maxpool ----------------
// 512 threads (8 waves), each wave owns 3 o-tiles of 16 -> 16 waves/CU for
// latency hiding of the strided scalar x loads.
__global__ __launch_bounds__(512, 2) void proj_kernel(
    const float* __restrict__ x, const __bf16* __restrict__ w_all,
    const float* __restrict__ b_all,
    __bf16* __restrict__ Q, __bf16* __restrict__ K, __bf16* __restrict__ VT)
{
    const int b    = blockIdx.x >> 7;
    const int tile = blockIdx.x & 127;
    const int n0   = tile * 64;
    const int w    = threadIdx.x >> 6;       // 0..7
    const int lane = threadIdx.x & 63;
    const int lq   = lane & 15;
    const int g    = lane >> 4;

    const float* xb = x + b * (C_ * NSP);

    f32x4 acc[4][3];
    #pragma unroll
    for (int a = 0; a < 4; ++a)
        #pragma unroll
        for (int o = 0; o < 3; ++o) acc[a][o] = (f32x4){0.f,0.f,0.f,0.f};

    #pragma unroll 1
    for (int ck = 0; ck < 8; ++ck) {
        const int cbase = ck*32 + g*8;
        bf16x8 afr[4];
        #pragma unroll
        for (int nf = 0; nf < 4; ++nf) {
            const int n = n0 + nf*16 + lq;
            const float* xp = xb + cbase*NSP + n;
            bf16x8 v;
            #pragma unroll
            for (int e = 0; e < 8; ++e) v[e] = (__bf16)xp[e*NSP];
            afr[nf] = v;
        }
        #pragma unroll
        for (int oi = 0; oi < 3; ++oi) {
            const int orow = (w*3 + oi)*16 + lq;
            bf16x8 bfr = *(const bf16x8*)(w_all + orow*256 + cbase);
            #pragma unroll
            for (int nf = 0; nf < 4; ++nf)
                acc[nf][oi] = __builtin_amdgcn_mfma_f32_16x16x32_bf16(afr[nf], bfr, acc[nf][oi], 0,0,0);
        }
    }

    const int t  = n0 >> 10;
    const int h0 = (n0 & 1023) >> 5;             // even
    const int kvrow0 = t*256 + (h0 >> 1)*16;

    #pragma unroll
    for (int oi = 0; oi < 3; ++oi) {
        const int ocol = (w*3 + oi)*16 + lq;
        const float bias = b_all[ocol];
        float v[4][4];
        #pragma unroll
        for (int nf = 0; nf < 4; ++nf)
            #pragma unroll
            for (int i = 0; i < 4; ++i) v[nf][i] = acc[nf][oi][i] + bias;

        const int seg = ocol >> 7;
        const int ol  = ocol & 127;
        if (seg == 0) {                      // theta -> Q[b][n][ol]
            #pragma unroll
            for (int nf = 0; nf < 4; ++nf)
                #pragma unroll
                for (int i = 0; i < 4; ++i) {
                    int n = n0 + nf*16 + g*4 + i;
                    Q[(b*NSP + n)*CI_ + ol] = (__bf16)v[nf][i];
                }
        } else if (seg == 1) {               // phi -> pool -> K[b][nkv][ol]
            #pragma unroll
            for (int nfp = 0; nfp < 2; ++nfp)
                #pragma unroll
                for (int j = 0; j < 2; ++j) {
                    float pv = fmaxf(fmaxf(v[nfp][2*j], v[nfp][2*j+1]),
                                     fmaxf(v[nfp+2][2*j], v[nfp+2][2*j+1]));
                    int wp = nfp*8 + g*2 + j;
                    K[(b*NKV + kvrow0 + wp)*CI_ + ol] = (__bf16)pv;
                }
        } else {                             // g -> pool -> VT[b][ol][nkv]
            #pragma unroll
            for (int nfp = 0; nfp < 2; ++nfp) {
                bf16x2 pk;
                #pragma unroll
                for (int j = 0; j < 2; ++j) {
                    float pv = fmaxf(fmaxf(v[nfp][2*j], v[nfp][2*j+1]),
                                     fmaxf(v[nfp+2][2*j], v[nfp+2][2*j+1]));
                    pk[j] = (__bf16)pv;
                }
                int wp = nfp*8 + g*2;
                *(bf16x2*)(VT + (b*CI_ + ol)*NKV + kvrow0 + wp) = pk;
            }
        }
    }
}

// ---------------- kernel 2: flash attention, LDS-staged K/V, 32q/wave, kv-split 2 ----------------
// Each block: 128 q x one kv-half (1024 rows, 32 tiles). 512 blocks = 2/CU so
// two blocks interleave per SIMD across barrier/DMA stalls (round-4 overlap)
// while keeping round-5's halved LDS traffic. Writes unnormalized O + (m,l).
__global__ __launch_bounds__(256, 2) void attn_kernel(
    const __bf16* __restrict__ Q, const __bf16* __restrict__ K,
    const __bf16* __restrict__ VT, __bf16* __restrict__ o_part,
    float* __restrict__ ml)
{
    __shared__ __bf16 kbuf[3][32*128];
    __shared__ __bf16 vbuf[3][128*32];
    __shared__ __bf16 plds[4][32][40];       // per-wave P buffer, 80B row stride

    const int b    = blockIdx.x >> 7;
    const int r    = blockIdx.x & 127;
    const int qt   = r >> 1;
    const int kvh  = r & 1;
    const int w    = threadIdx.x >> 6;
    const int lane = threadIdx.x & 63;
    const int lq   = lane & 15;
    const int g    = lane >> 4;
    const int q0   = qt*128 + w*32;
    const int kvbase = kvh * (NKV/2);
    const float LOG2E = 1.4426950408889634f;

    // Q fragments (B-operand: col q = lane&15, k = d), two q-subtiles
    bf16x8 qf[2][4];
    #pragma unroll
    for (int s = 0; s < 2; ++s) {
        const __bf16* qrow = Q + (size_t)(b*NSP + q0 + s*16 + lq)*CI_;
        #pragma unroll
        for (int kk = 0; kk < 4; ++kk) qf[s][kk] = *(const bf16x8*)(qrow + kk*32 + g*8);
    }

    float m_run[2] = {-1e30f, -1e30f}, l_run[2] = {0.f, 0.f};
    f32x4 oacc[2][8];
    #pragma unroll
    for (int s = 0; s < 2; ++s)
        #pragma unroll
        for (int d = 0; d < 8; ++d) oacc[s][d] = (f32x4){0.f,0.f,0.f,0.f};

    const __bf16* Kb0 = K  + (size_t)b*NKV*CI_;
    const __bf16* Vb0 = VT + (size_t)b*CI_*NKV;
    __bf16* pw = &plds[w][0][0];

    // stage one kv-tile into buffer bi: 4 global_load_lds per wave (2 K + 2 V)
    auto stage = [&](int bi, int kv0) {
        #pragma unroll
        for (int j = 0; j < 2; ++j) {
            int o   = w*2048 + j*1024 + lane*16;       // byte offset in 8KB tile
            int row = o >> 8;                          // K row (0..31)
            int c   = (o & 255) ^ ((row & 7) << 4);    // inverse swizzle on source
            const __bf16* src = Kb0 + (size_t)(kv0 + row)*CI_ + (c >> 1);
            gload_lds16(src, (char*)&kbuf[bi][0] + w*2048 + j*1024);
        }
        #pragma unroll
        for (int j = 0; j < 2; ++j) {
            int o    = w*2048 + j*1024 + lane*16;
            int row  = o >> 6;                         // V row (d, 0..127)
            int slot = (o >> 4) & 3;
            int kc   = slot ^ ((row >> 1) & 3);        // inverse swizzle on source
            const __bf16* src = Vb0 + (size_t)row*NKV + kv0 + kc*8;
            gload_lds16(src, (char*)&vbuf[bi][0] + w*2048 + j*1024);
        }
    };

    // prologue: tiles 0 and 1 in flight
    stage(0, kvbase);
    stage(1, kvbase + KVT);

    for (int t = 0; t < NTH; ++t) {
        // wait for tile t's 4 DMAs (tile t+1's stay in flight), then block sync
        asm volatile("s_waitcnt vmcnt(4)" ::: "memory");
        __builtin_amdgcn_s_barrier();
        __builtin_amdgcn_sched_barrier(0);

        // prefetch tile t+2 (clamped re-stage near the end keeps vmcnt math valid)
        {
            int tn = t + 2;
            int kvn = kvbase + (tn < NTH ? tn : NTH-1) * KVT;
            stage(tn % 3, kvn);
        }

        const int bi = t % 3;
        const char* kb = (const char*)&kbuf[bi][0];
        const char* vb = (const char*)&vbuf[bi][0];

        // QK^T: f^T[n][q] = sum_d K[n][d] Q[q][d]; each kf feeds both q-subtiles
        f32x4 facc[2][2];
        #pragma unroll
        for (int s = 0; s < 2; ++s)
            #pragma unroll
            for (int nf = 0; nf < 2; ++nf) facc[s][nf] = (f32x4){0.f,0.f,0.f,0.f};
        __builtin_amdgcn_s_setprio(1);
        #pragma unroll
        for (int kk = 0; kk < 4; ++kk) {
            #pragma unroll
            for (int nf = 0; nf < 2; ++nf) {
                int row = nf*16 + lq;
                int c   = (kk*64 + g*16) ^ ((row & 7) << 4);
                bf16x8 kf = *(const bf16x8*)(kb + row*256 + c);
                facc[0][nf] = __builtin_amdgcn_mfma_f32_16x16x32_bf16(kf, qf[0][kk], facc[0][nf], 0,0,0);
                facc[1][nf] = __builtin_amdgcn_mfma_f32_16x16x32_bf16(kf, qf[1][kk], facc[1][nf], 0,0,0);
            }
        }
        __builtin_amdgcn_s_setprio(0);

        // online softmax per q-subtile (tree reduce, defer-max)
        #pragma unroll
        for (int s = 0; s < 2; ++s) {
            float m0 = fmaxf(fmaxf(facc[s][0][0], facc[s][0][1]), fmaxf(facc[s][0][2], facc[s][0][3]));
            float m1 = fmaxf(fmaxf(facc[s][1][0], facc[s][1][1]), fmaxf(facc[s][1][2], facc[s][1][3]));
            float pmax = fmaxf(m0, m1);
            pmax = fmaxf(pmax, __shfl_xor(pmax, 16, 64));
            pmax = fmaxf(pmax, __shfl_xor(pmax, 32, 64));
            if (!__all(pmax - m_run[s] <= 8.f)) {
                float mnew = fmaxf(m_run[s], pmax);
                float corr = __builtin_amdgcn_exp2f((m_run[s] - mnew) * LOG2E);
                l_run[s] *= corr;
                #pragma unroll
                for (int d = 0; d < 8; ++d) {
                    oacc[s][d][0] *= corr; oacc[s][d][1] *= corr;
                    oacc[s][d][2] *= corr; oacc[s][d][3] *= corr;
                }
                m_run[s] = mnew;
            }
            float p[8];
            #pragma unroll
            for (int nf = 0; nf < 2; ++nf)
                #pragma unroll
                for (int i = 0; i < 4; ++i)
                    p[nf*4+i] = __builtin_amdgcn_exp2f((facc[s][nf][i] - m_run[s]) * LOG2E);
            float ps = ((p[0]+p[1]) + (p[2]+p[3])) + ((p[4]+p[5]) + (p[6]+p[7]));
            ps += __shfl_xor(ps, 16, 64);
            ps += __shfl_xor(ps, 32, 64);
            l_run[s] += ps;
            #pragma unroll
            for (int nf = 0; nf < 2; ++nf) {
                bf16x4 pk;
                #pragma unroll
                for (int i = 0; i < 4; ++i) pk[i] = (__bf16)p[nf*4+i];
                *(bf16x4*)(pw + (s*16 + lq)*40 + nf*16 + g*4) = pk;
            }
        }
        bf16x8 pb[2];
        #pragma unroll
        for (int s = 0; s < 2; ++s)
            pb[s] = *(const bf16x8*)(pw + (s*16 + lq)*40 + g*8);

        // yy^T[d][q] += VT[d][n] * P^T[n][q]; each vf feeds both q-subtiles
        __builtin_amdgcn_s_setprio(1);
        #pragma unroll
        for (int df = 0; df < 8; ++df) {
            int row = df*16 + lq;
            int cb  = (g*16) ^ (((row >> 1) & 3) << 4);
            bf16x8 vf = *(const bf16x8*)(vb + row*64 + cb);
            oacc[0][df] = __builtin_amdgcn_mfma_f32_16x16x32_bf16(vf, pb[0], oacc[0][df], 0,0,0);
            oacc[1][df] = __builtin_amdgcn_mfma_f32_16x16x32_bf16(vf, pb[1], oacc[1][df], 0,0,0);
        }
        __builtin_amdgcn_s_setprio(0);
    }

    // epilogue: unnormalized O (bf16) + per-row (m,l)
    #pragma unroll
    for (int s = 0; s < 2; ++s) {
        const int row = b*NSP + q0 + s*16 + lq;
        __bf16* orow = o_part + ((size_t)kvh*NROW + row)*CI_;
        #pragma unroll
        for (int df = 0; df < 8; ++df) {
            bf16x4 ov;
            #pragma unroll
            for (int i = 0; i < 4; ++i) ov[i] = (__bf16)oacc[s][df][i];
            *(bf16x4*)(orow + df*16 + g*4) = ov;
        }
        if (g == 0) {
            f32x2 v; v[0] = m_run[s]; v[1] = l_run[s];
            *(f32x2*)(ml + ((size_t)kvh*NROW + row)*2) = v;
        }
    }
}

// ---------------- kernel 3: flash-combine + out-proj + BN + residual ----------------
// A-fragment rows n: yy[n][d] = c1[n]*o1[n][d] + c2[n]*o2[n][d] with
// c_h = e^{m_h-M} / (e1*l1 + e2*l2)  (exact two-way flash merge, normalized).
__global__ __launch_bounds__(256, 2) void out_kernel(
    const __bf16* __restrict__ o_part, const float* __restrict__ ml,
    const __bf16* __restrict__ w2,
    const float* __restrict__ bnA, const float* __restrict__ bnB,
    const float* __restrict__ x, float* __restrict__ out)
{
    const int b    = blockIdx.x >> 7;
    const int tile = blockIdx.x & 127;
    const int n0   = tile * 64;
    const int w    = threadIdx.x >> 6;
    const int lane = threadIdx.x & 63;
    const int lq   = lane & 15;
    const int g    = lane >> 4;
    const float LOG2E = 1.4426950408889634f;

    // per-row combine coefficients (row = n0 + nf*16 + lq)
    float c1[4], c2[4];
    #pragma unroll
    for (int nf = 0; nf < 4; ++nf) {
        const size_t row = (size_t)b*NSP + n0 + nf*16 + lq;
        f32x2 ml1 = *(const f32x2*)(ml + row*2);
        f32x2 ml2 = *(const f32x2*)(ml + (NROW + row)*2);
        float M  = fmaxf(ml1[0], ml2[0]);
        float e1 = __builtin_amdgcn_exp2f((ml1[0] - M) * LOG2E);
        float e2 = __builtin_amdgcn_exp2f((ml2[0] - M) * LOG2E);
        float dinv = 1.f / (e1*ml1[1] + e2*ml2[1]);
        c1[nf] = e1 * dinv;
        c2[nf] = e2 * dinv;
    }

    f32x4 acc[4][4];   // [cf][nf], C[n][co]
    #pragma unroll
    for (int a = 0; a < 4; ++a)
        #pragma unroll
        for (int o = 0; o < 4; ++o) acc[a][o] = (f32x4){0.f,0.f,0.f,0.f};

    #pragma unroll
    for (int kk = 0; kk < 4; ++kk) {
        bf16x8 afr[4];   // combined yy n-row fragments (A-operand)
        #pragma unroll
        for (int nf = 0; nf < 4; ++nf) {
            const size_t off = ((size_t)b*NSP + n0 + nf*16 + lq)*CI_ + kk*32 + g*8;
            bf16x8 o1 = *(const bf16x8*)(o_part + off);
            bf16x8 o2 = *(const bf16x8*)(o_part + (size_t)NROW*CI_ + off);
            bf16x8 af;
            #pragma unroll
            for (int e = 0; e < 8; ++e)
                af[e] = (__bf16)(c1[nf]*(float)o1[e] + c2[nf]*(float)o2[e]);
            afr[nf] = af;
        }
        #pragma unroll
        for (int cf = 0; cf < 4; ++cf) {
            const int corow = (w*4 + cf)*16 + lq;
            bf16x8 bfr = *(const bf16x8*)(w2 + corow*CI_ + kk*32 + g*8);  // B-operand (cols co)
            #pragma unroll
            for (int nf = 0; nf < 4; ++nf)
                acc[cf][nf] = __builtin_amdgcn_mfma_f32_16x16x32_bf16(afr[nf], bfr, acc[cf][nf], 0,0,0);
        }
    }

    #pragma unroll
    for (int cf = 0; cf < 4; ++cf) {
        const int co = (w*4 + cf)*16 + lq;
        const float A = bnA[co], Bv = bnB[co];
        #pragma unroll
        for (int nf = 0; nf < 4; ++nf) {
            const int n = n0 + nf*16 + g*4;
            size_t idx = (size_t)(b*C_ + co)*NSP + n;
            f32x4 xv = *(const f32x4*)(x + idx);
            f32x4 ov;
            #pragma unroll
            for (int i = 0; i < 4; ++i) ov[i] = acc[cf][nf][i]*A + Bv + xv[i];
            *(f32x4*)(out + idx) = ov;
        }
    }
}

// ---------------- launcher ----------------
extern "C" void kernel_launch(void* const* d_in, const int* in_sizes, int n_in,
                              void* d_out, int out_size, void* d_ws, size_t ws_size,
                              hipStream_t stream)
{
    const float* x    = (const float*)d_in[0];
    const float* g_w  = (const float*)d_in[1];
    const float* g_b  = (const float*)d_in[2];
    const float* th_w = (const float*)d_in[3];
    const float* th_b = (const float*)d_in[4];
    const float* ph_w = (const float*)d_in[5];
    const float* ph_b = (const float*)d_in[6];
    const float* w_w  = (const float*)d_in[7];
    const float* w_b  = (const float*)d_in[8];
    const float* bn_g = (const float*)d_in[9];
    const float* bn_be= (const float*)d_in[10];
    const float* bn_m = (const float*)d_in[11];
    const float* bn_v = (const float*)d_in[12];

    char* ws = (char*)d_ws;
    size_t off = 0;
    auto alloc = [&](size_t bytes) -> void* {
        void* p = ws + off;
        off += (bytes + 255) & ~(size_t)255;
        return p;
    };
    __bf16* w_all = (__bf16*)alloc(384*256*2);
    __bf16* w2    = (__bf16*)alloc(256*128*2);
    float*  b_all = (float*) alloc(384*4);
    float*  bnA   = (float*) alloc(256*4);
    float*  bnB   = (float*) alloc(256*4);
    __bf16* Qb    = (__bf16*)alloc((size_t)NROW*CI_*2);
    __bf16* Kb    = (__bf16*)alloc((size_t)NB*NKV*CI_*2);
    __bf16* Vt    = (__bf16*)alloc((size_t)NB*CI_*NKV*2);
    __bf16* oPart = (__bf16*)alloc((size_t)2*NROW*CI_*2);
    float*  mlB   = (float*) alloc((size_t)2*NROW*2*4);

    prep_kernel<<<515, 256, 0, stream>>>(g_w, g_b, th_w, th_b, ph_w, ph_b, w_w, w_b,
                                         bn_g, bn_be, bn_m, bn_v,
                                         w_all, w2, b_all, bnA, bnB);
    proj_kernel<<<512, 512, 0, stream>>>(x, w_all, b_all, Qb, Kb, Vt);
    attn_kernel<<<512, 256, 0, stream>>>(Qb, Kb, Vt, oPart, mlB);
    out_kernel <<<512, 256, 0, stream>>>(oPart, mlB, w2, bnA, bnB, x, (float*)d_out);
}

// Round 8
// 194.945 us; speedup vs baseline: 1.1225x; 1.0052x over previous
//
#include <hip/hip_runtime.h>
#include <hip/hip_bf16.h>

typedef __bf16 bf16x8 __attribute__((ext_vector_type(8)));
typedef __bf16 bf16x4 __attribute__((ext_vector_type(4)));
typedef __bf16 bf16x2 __attribute__((ext_vector_type(2)));
typedef float  f32x4  __attribute__((ext_vector_type(4)));
typedef float  f32x2  __attribute__((ext_vector_type(2)));

#define NB   4
#define C_   256
#define CI_  128
#define NSP  8192   // 8*32*32
#define NKV  2048   // 8*16*16
#define KVT  32     // kv rows per tile
#define NTH  ((NKV/2)/KVT)   // tiles per kv-half = 32
#define NROW (NB*NSP)        // total q rows

// direct global->LDS DMA, 16B per lane. g: per-lane source; l: wave-uniform dest.
__device__ __forceinline__ void gload_lds16(const void* g, void* l) {
    __builtin_amdgcn_global_load_lds(
        (const __attribute__((address_space(1))) void*)(unsigned long long)(uintptr_t)g,
        (__attribute__((address_space(3))) void*)(unsigned)(uintptr_t)l,
        16, 0, 0);
}

// ---------------- kernel 0: weight prep (bf16 cast, BN fold) ----------------
__global__ __launch_bounds__(256) void prep_kernel(
    const float* __restrict__ g_w,  const float* __restrict__ g_b,
    const float* __restrict__ th_w, const float* __restrict__ th_b,
    const float* __restrict__ ph_w, const float* __restrict__ ph_b,
    const float* __restrict__ w_w,  const float* __restrict__ w_b,
    const float* __restrict__ bn_g, const float* __restrict__ bn_be,
    const float* __restrict__ bn_m, const float* __restrict__ bn_v,
    __bf16* __restrict__ w_all, __bf16* __restrict__ w2,
    float* __restrict__ b_all, float* __restrict__ bnA, float* __restrict__ bnB)
{
    int idx = blockIdx.x * 256 + threadIdx.x;
    if (idx < 98304) {                       // w_all: [theta;phi;g] 384x256
        int o = idx >> 8, c = idx & 255;
        float v;
        if (o < 128)      v = th_w[o*256 + c];
        else if (o < 256) v = ph_w[(o-128)*256 + c];
        else              v = g_w[(o-256)*256 + c];
        w_all[idx] = (__bf16)v;
    } else if (idx < 131072) {               // w2: 256x128
        int j = idx - 98304;
        w2[j] = (__bf16)w_w[j];
    } else if (idx < 131456) {               // b_all: 384
        int k = idx - 131072;
        float v;
        if (k < 128) v = th_b[k]; else if (k < 256) v = ph_b[k-128]; else v = g_b[k-256];
        b_all[k] = v;
    } else if (idx < 131712) {               // BN fold (+w_b): 256
        int m = idx - 131456;
        float sc = bn_g[m] * rsqrtf(bn_v[m] + 1e-5f);
        bnA[m] = sc;
        bnB[m] = w_b[m]*sc + bn_be[m] - bn_m[m]*sc;
    }
}

// ---------------- kernel 1: fused 3-way projection + (1,2,2) maxpool ----------------
// x tile staged ONCE per block into LDS as bf16 xT[64 n][256 c], XOR-swizzled
// (byte ^= (n&7)<<4). Kills the 8x redundant per-wave global fragment loads.
// 512 threads (8 waves x 3 o-tiles); launch_bounds(512,4) -> 2 blocks/CU.
__global__ __launch_bounds__(512, 4) void proj_kernel(
    const float* __restrict__ x, const __bf16* __restrict__ w_all,
    const float* __restrict__ b_all,
    __bf16* __restrict__ Q, __bf16* __restrict__ K, __bf16* __restrict__ VT)
{
    __shared__ __bf16 xt[64*256];            // 32 KB, swizzled

    const int b    = blockIdx.x >> 7;
    const int tile = blockIdx.x & 127;
    const int n0   = tile * 64;
    const int tid  = threadIdx.x;
    const int w    = tid >> 6;               // 0..7
    const int lane = tid & 63;
    const int lq   = lane & 15;
    const int g    = lane >> 4;

    const float* xb = x + b * (C_ * NSP);

    // ---- stage: 4 chunks/thread, each 8 consecutive c at fixed n ----
    {
        const int n = tid & 63;              // lane-consecutive -> coalesced
        const int cw = tid >> 6;
        #pragma unroll
        for (int j = 0; j < 4; ++j) {
            const int cchunk = j*8 + cw;     // 0..31
            const float* xp = xb + (size_t)(cchunk*8)*NSP + n0 + n;
            bf16x8 v;
            #pragma unroll
            for (int e = 0; e < 8; ++e) v[e] = (__bf16)xp[(size_t)e*NSP];
            *(bf16x8*)((char*)xt + n*512 + ((cchunk*16) ^ ((n & 7) << 4))) = v;
        }
    }
    __syncthreads();

    f32x4 acc[4][3];
    #pragma unroll
    for (int a = 0; a < 4; ++a)
        #pragma unroll
        for (int o = 0; o < 3; ++o) acc[a][o] = (f32x4){0.f,0.f,0.f,0.f};

    #pragma unroll 2
    for (int ck = 0; ck < 8; ++ck) {
        const int cbase = ck*32 + g*8;
        bf16x8 afr[4];
        #pragma unroll
        for (int nf = 0; nf < 4; ++nf) {
            const int n = nf*16 + lq;
            afr[nf] = *(const bf16x8*)((const char*)xt + n*512 +
                          ((ck*64 + g*16) ^ ((n & 7) << 4)));
        }
        #pragma unroll
        for (int oi = 0; oi < 3; ++oi) {
            const int orow = (w*3 + oi)*16 + lq;
            bf16x8 bfr = *(const bf16x8*)(w_all + orow*256 + cbase);
            #pragma unroll
            for (int nf = 0; nf < 4; ++nf)
                acc[nf][oi] = __builtin_amdgcn_mfma_f32_16x16x32_bf16(afr[nf], bfr, acc[nf][oi], 0,0,0);
        }
    }

    const int t  = n0 >> 10;
    const int h0 = (n0 & 1023) >> 5;             // even
    const int kvrow0 = t*256 + (h0 >> 1)*16;

    #pragma unroll
    for (int oi = 0; oi < 3; ++oi) {
        const int ocol = (w*3 + oi)*16 + lq;
        const float bias = b_all[ocol];
        float v[4][4];
        #pragma unroll
        for (int nf = 0; nf < 4; ++nf)
            #pragma unroll
            for (int i = 0; i < 4; ++i) v[nf][i] = acc[nf][oi][i] + bias;

        const int seg = ocol >> 7;
        const int ol  = ocol & 127;
        if (seg == 0) {                      // theta -> Q[b][n][ol]
            #pragma unroll
            for (int nf = 0; nf < 4; ++nf)
                #pragma unroll
                for (int i = 0; i < 4; ++i) {
                    int n = n0 + nf*16 + g*4 + i;
                    Q[(b*NSP + n)*CI_ + ol] = (__bf16)v[nf][i];
                }
        } else if (seg == 1) {               // phi -> pool -> K[b][nkv][ol]
            #pragma unroll
            for (int nfp = 0; nfp < 2; ++nfp)
                #pragma unroll
                for (int j = 0; j < 2; ++j) {
                    float pv = fmaxf(fmaxf(v[nfp][2*j], v[nfp][2*j+1]),
                                     fmaxf(v[nfp+2][2*j], v[nfp+2][2*j+1]));
                    int wp = nfp*8 + g*2 + j;
                    K[(b*NKV + kvrow0 + wp)*CI_ + ol] = (__bf16)pv;
                }
        } else {                             // g -> pool -> VT[b][ol][nkv]
            #pragma unroll
            for (int nfp = 0; nfp < 2; ++nfp) {
                bf16x2 pk;
                #pragma unroll
                for (int j = 0; j < 2; ++j) {
                    float pv = fmaxf(fmaxf(v[nfp][2*j], v[nfp][2*j+1]),
                                     fmaxf(v[nfp+2][2*j], v[nfp+2][2*j+1]));
                    pk[j] = (__bf16)pv;
                }
                int wp = nfp*8 + g*2;
                *(bf16x2*)(VT + (b*CI_ + ol)*NKV + kvrow0 + wp) = pk;
            }
        }
    }
}

// ---------------- kernel 2: flash attention, LDS-staged K/V, 32q/wave, kv-split 2 ----------------
__global__ __launch_bounds__(256, 2) void attn_kernel(
    const __bf16* __restrict__ Q, const __bf16* __restrict__ K,
    const __bf16* __restrict__ VT, __bf16* __restrict__ o_part,
    float* __restrict__ ml)
{
    __shared__ __bf16 kbuf[3][32*128];
    __shared__ __bf16 vbuf[3][128*32];
    __shared__ __bf16 plds[4][32][40];       // per-wave P buffer, 80B row stride

    const int b    = blockIdx.x >> 7;
    const int r    = blockIdx.x & 127;
    const int qt   = r >> 1;
    const int kvh  = r & 1;
    const int w    = threadIdx.x >> 6;
    const int lane = threadIdx.x & 63;
    const int lq   = lane & 15;
    const int g    = lane >> 4;
    const int q0   = qt*128 + w*32;
    const int kvbase = kvh * (NKV/2);
    const float LOG2E = 1.4426950408889634f;

    // Q fragments (B-operand: col q = lane&15, k = d), two q-subtiles
    bf16x8 qf[2][4];
    #pragma unroll
    for (int s = 0; s < 2; ++s) {
        const __bf16* qrow = Q + (size_t)(b*NSP + q0 + s*16 + lq)*CI_;
        #pragma unroll
        for (int kk = 0; kk < 4; ++kk) qf[s][kk] = *(const bf16x8*)(qrow + kk*32 + g*8);
    }

    float m_run[2] = {-1e30f, -1e30f}, l_run[2] = {0.f, 0.f};
    f32x4 oacc[2][8];
    #pragma unroll
    for (int s = 0; s < 2; ++s)
        #pragma unroll
        for (int d = 0; d < 8; ++d) oacc[s][d] = (f32x4){0.f,0.f,0.f,0.f};

    const __bf16* Kb0 = K  + (size_t)b*NKV*CI_;
    const __bf16* Vb0 = VT + (size_t)b*CI_*NKV;
    __bf16* pw = &plds[w][0][0];

    // stage one kv-tile into buffer bi: 4 global_load_lds per wave (2 K + 2 V)
    auto stage = [&](int bi, int kv0) {
        #pragma unroll
        for (int j = 0; j < 2; ++j) {
            int o   = w*2048 + j*1024 + lane*16;       // byte offset in 8KB tile
            int row = o >> 8;                          // K row (0..31)
            int c   = (o & 255) ^ ((row & 7) << 4);    // inverse swizzle on source
            const __bf16* src = Kb0 + (size_t)(kv0 + row)*CI_ + (c >> 1);
            gload_lds16(src, (char*)&kbuf[bi][0] + w*2048 + j*1024);
        }
        #pragma unroll
        for (int j = 0; j < 2; ++j) {
            int o    = w*2048 + j*1024 + lane*16;
            int row  = o >> 6;                         // V row (d, 0..127)
            int slot = (o >> 4) & 3;
            int kc   = slot ^ ((row >> 1) & 3);        // inverse swizzle on source
            const __bf16* src = Vb0 + (size_t)row*NKV + kv0 + kc*8;
            gload_lds16(src, (char*)&vbuf[bi][0] + w*2048 + j*1024);
        }
    };

    // prologue: tiles 0 and 1 in flight
    stage(0, kvbase);
    stage(1, kvbase + KVT);

    for (int t = 0; t < NTH; ++t) {
        // wait for tile t's 4 DMAs (tile t+1's stay in flight), then block sync
        asm volatile("s_waitcnt vmcnt(4)" ::: "memory");
        __builtin_amdgcn_s_barrier();
        __builtin_amdgcn_sched_barrier(0);

        // prefetch tile t+2 (clamped re-stage near the end keeps vmcnt math valid)
        {
            int tn = t + 2;
            int kvn = kvbase + (tn < NTH ? tn : NTH-1) * KVT;
            stage(tn % 3, kvn);
        }

        const int bi = t % 3;
        const char* kb = (const char*)&kbuf[bi][0];
        const char* vb = (const char*)&vbuf[bi][0];

        // QK^T: f^T[n][q] = sum_d K[n][d] Q[q][d]; each kf feeds both q-subtiles
        f32x4 facc[2][2];
        #pragma unroll
        for (int s = 0; s < 2; ++s)
            #pragma unroll
            for (int nf = 0; nf < 2; ++nf) facc[s][nf] = (f32x4){0.f,0.f,0.f,0.f};
        __builtin_amdgcn_s_setprio(1);
        #pragma unroll
        for (int kk = 0; kk < 4; ++kk) {
            #pragma unroll
            for (int nf = 0; nf < 2; ++nf) {
                int row = nf*16 + lq;
                int c   = (kk*64 + g*16) ^ ((row & 7) << 4);
                bf16x8 kf = *(const bf16x8*)(kb + row*256 + c);
                facc[0][nf] = __builtin_amdgcn_mfma_f32_16x16x32_bf16(kf, qf[0][kk], facc[0][nf], 0,0,0);
                facc[1][nf] = __builtin_amdgcn_mfma_f32_16x16x32_bf16(kf, qf[1][kk], facc[1][nf], 0,0,0);
            }
        }
        __builtin_amdgcn_s_setprio(0);

        // online softmax per q-subtile (tree reduce, defer-max)
        #pragma unroll
        for (int s = 0; s < 2; ++s) {
            float m0 = fmaxf(fmaxf(facc[s][0][0], facc[s][0][1]), fmaxf(facc[s][0][2], facc[s][0][3]));
            float m1 = fmaxf(fmaxf(facc[s][1][0], facc[s][1][1]), fmaxf(facc[s][1][2], facc[s][1][3]));
            float pmax = fmaxf(m0, m1);
            pmax = fmaxf(pmax, __shfl_xor(pmax, 16, 64));
            pmax = fmaxf(pmax, __shfl_xor(pmax, 32, 64));
            if (!__all(pmax - m_run[s] <= 8.f)) {
                float mnew = fmaxf(m_run[s], pmax);
                float corr = __builtin_amdgcn_exp2f((m_run[s] - mnew) * LOG2E);
                l_run[s] *= corr;
                #pragma unroll
                for (int d = 0; d < 8; ++d) {
                    oacc[s][d][0] *= corr; oacc[s][d][1] *= corr;
                    oacc[s][d][2] *= corr; oacc[s][d][3] *= corr;
                }
                m_run[s] = mnew;
            }
            float p[8];
            #pragma unroll
            for (int nf = 0; nf < 2; ++nf)
                #pragma unroll
                for (int i = 0; i < 4; ++i)
                    p[nf*4+i] = __builtin_amdgcn_exp2f((facc[s][nf][i] - m_run[s]) * LOG2E);
            float ps = ((p[0]+p[1]) + (p[2]+p[3])) + ((p[4]+p[5]) + (p[6]+p[7]));
            ps += __shfl_xor(ps, 16, 64);
            ps += __shfl_xor(ps, 32, 64);
            l_run[s] += ps;
            #pragma unroll
            for (int nf = 0; nf < 2; ++nf) {
                bf16x4 pk;
                #pragma unroll
                for (int i = 0; i < 4; ++i) pk[i] = (__bf16)p[nf*4+i];
                *(bf16x4*)(pw + (s*16 + lq)*40 + nf*16 + g*4) = pk;
            }
        }
        bf16x8 pb[2];
        #pragma unroll
        for (int s = 0; s < 2; ++s)
            pb[s] = *(const bf16x8*)(pw + (s*16 + lq)*40 + g*8);

        // yy^T[d][q] += VT[d][n] * P^T[n][q]; each vf feeds both q-subtiles
        __builtin_amdgcn_s_setprio(1);
        #pragma unroll
        for (int df = 0; df < 8; ++df) {
            int row = df*16 + lq;
            int cb  = (g*16) ^ (((row >> 1) & 3) << 4);
            bf16x8 vf = *(const bf16x8*)(vb + row*64 + cb);
            oacc[0][df] = __builtin_amdgcn_mfma_f32_16x16x32_bf16(vf, pb[0], oacc[0][df], 0,0,0);
            oacc[1][df] = __builtin_amdgcn_mfma_f32_16x16x32_bf16(vf, pb[1], oacc[1][df], 0,0,0);
        }
        __builtin_amdgcn_s_setprio(0);
    }

    // epilogue: unnormalized O (bf16) + per-row (m,l)
    #pragma unroll
    for (int s = 0; s < 2; ++s) {
        const int row = b*NSP + q0 + s*16 + lq;
        __bf16* orow = o_part + ((size_t)kvh*NROW + row)*CI_;
        #pragma unroll
        for (int df = 0; df < 8; ++df) {
            bf16x4 ov;
            #pragma unroll
            for (int i = 0; i < 4; ++i) ov[i] = (__bf16)oacc[s][df][i];
            *(bf16x4*)(orow + df*16 + g*4) = ov;
        }
        if (g == 0) {
            f32x2 v; v[0] = m_run[s]; v[1] = l_run[s];
            *(f32x2*)(ml + ((size_t)kvh*NROW + row)*2) = v;
        }
    }
}

// ---------------- kernel 3: flash-combine + out-proj + BN + residual ----------------
// 32-n tiles -> grid 1024 = 4 blocks/CU (16 waves/CU) for the memory-bound phase.
__global__ __launch_bounds__(256, 4) void out_kernel(
    const __bf16* __restrict__ o_part, const float* __restrict__ ml,
    const __bf16* __restrict__ w2,
    const float* __restrict__ bnA, const float* __restrict__ bnB,
    const float* __restrict__ x, float* __restrict__ out)
{
    const int b    = blockIdx.x >> 8;
    const int tile = blockIdx.x & 255;
    const int n0   = tile * 32;
    const int w    = threadIdx.x >> 6;
    const int lane = threadIdx.x & 63;
    const int lq   = lane & 15;
    const int g    = lane >> 4;
    const float LOG2E = 1.4426950408889634f;

    // per-row combine coefficients (row = n0 + nf*16 + lq)
    float c1[2], c2[2];
    #pragma unroll
    for (int nf = 0; nf < 2; ++nf) {
        const size_t row = (size_t)b*NSP + n0 + nf*16 + lq;
        f32x2 ml1 = *(const f32x2*)(ml + row*2);
        f32x2 ml2 = *(const f32x2*)(ml + (NROW + row)*2);
        float M  = fmaxf(ml1[0], ml2[0]);
        float e1 = __builtin_amdgcn_exp2f((ml1[0] - M) * LOG2E);
        float e2 = __builtin_amdgcn_exp2f((ml2[0] - M) * LOG2E);
        float dinv = 1.f / (e1*ml1[1] + e2*ml2[1]);
        c1[nf] = e1 * dinv;
        c2[nf] = e2 * dinv;
    }

    f32x4 acc[4][2];   // [cf][nf], C[n][co]
    #pragma unroll
    for (int a = 0; a < 4; ++a)
        #pragma unroll
        for (int o = 0; o < 2; ++o) acc[a][o] = (f32x4){0.f,0.f,0.f,0.f};

    #pragma unroll
    for (int kk = 0; kk < 4; ++kk) {
        bf16x8 afr[2];   // combined yy n-row fragments (A-operand)
        #pragma unroll
        for (int nf = 0; nf < 2; ++nf) {
            const size_t off = ((size_t)b*NSP + n0 + nf*16 + lq)*CI_ + kk*32 + g*8;
            bf16x8 o1 = *(const bf16x8*)(o_part + off);
            bf16x8 o2 = *(const bf16x8*)(o_part + (size_t)NROW*CI_ + off);
            bf16x8 af;
            #pragma unroll
            for (int e = 0; e < 8; ++e)
                af[e] = (__bf16)(c1[nf]*(float)o1[e] + c2[nf]*(float)o2[e]);
            afr[nf] = af;
        }
        #pragma unroll
        for (int cf = 0; cf < 4; ++cf) {
            const int corow = (w*4 + cf)*16 + lq;
            bf16x8 bfr = *(const bf16x8*)(w2 + corow*CI_ + kk*32 + g*8);  // B-operand (cols co)
            #pragma unroll
            for (int nf = 0; nf < 2; ++nf)
                acc[cf][nf] = __builtin_amdgcn_mfma_f32_16x16x32_bf16(afr[nf], bfr, acc[cf][nf], 0,0,0);
        }
    }

    #pragma unroll
    for (int cf = 0; cf < 4; ++cf) {
        const int co = (w*4 + cf)*16 + lq;
        const float A = bnA[co], Bv = bnB[co];
        #pragma unroll
        for (int nf = 0; nf < 2; ++nf) {
            const int n = n0 + nf*16 + g*4;
            size_t idx = (size_t)(b*C_ + co)*NSP + n;
            f32x4 xv = *(const f32x4*)(x + idx);
            f32x4 ov;
            #pragma unroll
            for (int i = 0; i < 4; ++i) ov[i] = acc[cf][nf][i]*A + Bv + xv[i];
            *(f32x4*)(out + idx) = ov;
        }
    }
}

// ---------------- launcher ----------------
extern "C" void kernel_launch(void* const* d_in, const int* in_sizes, int n_in,
                              void* d_out, int out_size, void* d_ws, size_t ws_size,
                              hipStream_t stream)
{
    const float* x    = (const float*)d_in[0];
    const float* g_w  = (const float*)d_in[1];
    const float* g_b  = (const float*)d_in[2];
    const float* th_w = (const float*)d_in[3];
    const float* th_b = (const float*)d_in[4];
    const float* ph_w = (const float*)d_in[5];
    const float* ph_b = (const float*)d_in[6];
    const float* w_w  = (const float*)d_in[7];
    const float* w_b  = (const float*)d_in[8];
    const float* bn_g = (const float*)d_in[9];
    const float* bn_be= (const float*)d_in[10];
    const float* bn_m = (const float*)d_in[11];
    const float* bn_v = (const float*)d_in[12];

    char* ws = (char*)d_ws;
    size_t off = 0;
    auto alloc = [&](size_t bytes) -> void* {
        void* p = ws + off;
        off += (bytes + 255) & ~(size_t)255;
        return p;
    };
    __bf16* w_all = (__bf16*)alloc(384*256*2);
    __bf16* w2    = (__bf16*)alloc(256*128*2);
    float*  b_all = (float*) alloc(384*4);
    float*  bnA   = (float*) alloc(256*4);
    float*  bnB   = (float*) alloc(256*4);
    __bf16* Qb    = (__bf16*)alloc((size_t)NROW*CI_*2);
    __bf16* Kb    = (__bf16*)alloc((size_t)NB*NKV*CI_*2);
    __bf16* Vt    = (__bf16*)alloc((size_t)NB*CI_*NKV*2);
    __bf16* oPart = (__bf16*)alloc((size_t)2*NROW*CI_*2);
    float*  mlB   = (float*) alloc((size_t)2*NROW*2*4);

    prep_kernel<<<515, 256, 0, stream>>>(g_w, g_b, th_w, th_b, ph_w, ph_b, w_w, w_b,
                                         bn_g, bn_be, bn_m, bn_v,
                                         w_all, w2, b_all, bnA, bnB);
    proj_kernel<<<512, 512, 0, stream>>>(x, w_all, b_all, Qb, Kb, Vt);
    attn_kernel<<<512, 256, 0, stream>>>(Qb, Kb, Vt, oPart, mlB);
    out_kernel <<<1024, 256, 0, stream>>>(oPart, mlB, w2, bnA, bnB, x, (float*)d_out);
}